// Round 6
// baseline (388.006 us; speedup 1.0000x reference)
//
#include <hip/hip_runtime.h>
#include <math.h>

// B=512, T=256, C=384, H=64. One block = one batch, 512 thr = 8 waves (2/SIMD).
// R9: x NEVER touches LDS. Each wave loads its A-fragments (8 consecutive
// floats of its own rows, 128B-aligned per quad) directly from global with a
// 2-slot register pipeline, packs hi/lo in-register. W keeps R8's async
// global_load_lds double-buffer (1 barrier/chunk). Removes per chunk: 32KB
// LDS writes + 64 A-frag ds_reads + staging remap. Evidence: R4-R8 all sit
// ~20% on every pipe; phase-1 LDS reads (~2690cyc) co-critical with MFMA
// (~2790cyc) per chunk at 2 waves/SIMD; x round-trip was 1/3 of LDS traffic.
// Numerics unchanged: 3-term bf16 hi/lo split for x,W,q,k; single bf16 P,V.
#define B_ 512
#define T_ 256
#define C_ 384
#define H_ 64

typedef __attribute__((ext_vector_type(8))) short bf16x8;
typedef __attribute__((ext_vector_type(4))) float f32x4;
typedef __attribute__((ext_vector_type(4))) unsigned u32x4;

#define MFMA16(a, b, c) __builtin_amdgcn_mfma_f32_16x16x32_bf16((a), (b), (c), 0, 0, 0)

// ---- LDS map (bytes), total 144384 <= 163840.
// Phase 1: W double-buffer WBUF(0)@0, WBUF(1)@32768 (each 32768B:
//   WQH,WQL,WKH,WKL,WVH,WVL @5120 each + 2048 pad). No x staging.
// Phase 2 (aliased over W bufs, live only after the post-loop barrier):
//   KHI@0 khi[256][72], KLO@36864, VT@73728 vT[64][264],
//   QS(s)=107520+s*9216 (4 slots, two shifts), PS(w)=107520+w*2304.
#define WBUF(i)  ((unsigned)(i)*32768u)
#define SM_KHI   0u
#define SM_KLO   36864u
#define SM_VT    73728u
#define SM_QS(s) (107520u + (unsigned)(s)*9216u)
#define SM_PS(w) (107520u + (unsigned)(w)*2304u)
#define SM_BYTES 144384u
#define WCHUNK   32768u   // ws bytes per K-chunk (30720 live + pad)

static __device__ __forceinline__ unsigned short bhi(float x) {
    return (unsigned short)(__float_as_uint(x) >> 16);            // truncate
}
static __device__ __forceinline__ unsigned short blo(float x) {
    float h = __uint_as_float((__float_as_uint(x) >> 16) << 16);
    return (unsigned short)(__float_as_uint(x - h) >> 16);        // residual
}
static __device__ __forceinline__ unsigned short brne(float x) { // round-NE
    unsigned u = __float_as_uint(x);
    return (unsigned short)((u + 0x7FFFu + ((u >> 16) & 1u)) >> 16);
}
static __device__ __forceinline__ unsigned pk_hi(float a, float b) {
    return (unsigned)bhi(a) | ((unsigned)bhi(b) << 16);
}
static __device__ __forceinline__ unsigned pk_lo(float a, float b) {
    return (unsigned)blo(a) | ((unsigned)blo(b) << 16);
}

// ---- Pre-kernel: pack W -> ws in staged-transposed layout, once for all blocks.
// ws[cc*32768 + m*10240 + part*5120 + h*80 + c'*2] = {bhi,blo}(W_m[cc*32+c'][h])
__global__ __launch_bounds__(256)
void wprep(const float* __restrict__ Wq, const float* __restrict__ Wk,
           const float* __restrict__ Wv, unsigned char* __restrict__ ws)
{
    const int cc = blockIdx.x / 3, m = blockIdx.x % 3;
    const float* W = (m == 0) ? Wq : (m == 1) ? Wk : Wv;
    const int tid = threadIdx.x;           // 256 threads
    const int c   = tid >> 3;              // 0..31 (c within chunk)
    const int h0  = (tid & 7) * 8;         // 8 h per thread
    const float* src = W + (size_t)(cc * 32 + c) * H_ + h0;
    unsigned char* dst = ws + (size_t)cc * WCHUNK + (size_t)m * 10240u;
    #pragma unroll
    for (int j = 0; j < 8; ++j) {
        const float v = src[j];
        *(unsigned short*)(dst +         (unsigned)((h0 + j) * 80 + c * 2)) = bhi(v);
        *(unsigned short*)(dst + 5120u + (unsigned)((h0 + j) * 80 + c * 2)) = blo(v);
    }
}

__global__ __launch_bounds__(512, 2)
void head_mfma(const float* __restrict__ x,
               const unsigned char* __restrict__ wpack,
               float* __restrict__ out)
{
    __shared__ __align__(16) unsigned char sm[SM_BYTES];

    const int tid  = threadIdx.x;
    const int b    = blockIdx.x;
    const int w    = tid >> 6;        // wave 0..7
    const int lane = tid & 63;
    const int l15  = lane & 15;
    const int quad = lane >> 4;
    const int rA   = w * 16;          // tile A rows [rA, rA+16)
    const int rB   = 240 - w * 16;    // tile B rows [rB, rB+16)

    // ================= Phase 1: q,k,v projections via MFMA =================
    f32x4 qac[2][4], kac[2][4], vac[2][4];
    #pragma unroll
    for (int mt = 0; mt < 2; ++mt)
        #pragma unroll
        for (int nt = 0; nt < 4; ++nt) {
            f32x4 z = {0.f, 0.f, 0.f, 0.f};
            qac[mt][nt] = z; kac[mt][nt] = z; vac[mt][nt] = z;
        }

    // per-lane A-fragment sources: row (rA|rB)+l15, 8 consecutive floats at
    // col cc*32 + quad*8. 4 lanes (quads) cover a 128B-aligned row segment.
    const float* xA = x + ((size_t)b * T_ + rA + l15) * C_ + quad * 8;
    const float* xB = x + ((size_t)b * T_ + rB + l15) * C_ + quad * 8;

    float4 xf[2][2][2];   // [slot][tile][half] 2-deep register pipeline

#define LOADX(S, CC)                                                          \
    {                                                                         \
        const float4* pA = (const float4*)(xA + (CC) * 32);                   \
        const float4* pB = (const float4*)(xB + (CC) * 32);                   \
        xf[S][0][0] = pA[0]; xf[S][0][1] = pA[1];                             \
        xf[S][1][0] = pB[0]; xf[S][1][1] = pB[1];                             \
    }
// Async W staging: per-wave uniform LDS base + lane*16, linear layout.
#define W_LDS(CC, BUF)                                                        \
    {                                                                         \
        const unsigned char* gw = wpack + (size_t)(CC) * WCHUNK;              \
        _Pragma("unroll")                                                     \
        for (int j = 0; j < 4; ++j)                                           \
            __builtin_amdgcn_global_load_lds(                                 \
                (const __attribute__((address_space(1))) void*)               \
                    (gw + (unsigned)(j*512 + tid) * 16u),                     \
                (__attribute__((address_space(3))) void*)                     \
                    &sm[(BUF) + (unsigned)(j*512 + tid) * 16u],               \
                16, 0, 0);                                                    \
    }

    // ---- prologue: W chunk0 async -> buf0; x chunks 0,1 into reg slots
    W_LDS(0, WBUF(0))
    LOADX(0, 0)
    LOADX(1, 1)
    __syncthreads();   // drains W chunk0 (and x loads)

    #pragma unroll 1
    for (int cc = 0; cc < 12; ++cc) {
        const unsigned bc = WBUF(cc & 1);   // compute W buffer
        if (cc < 11) W_LDS(cc + 1, WBUF((cc & 1) ^ 1))   // drains at end barrier

        // ---- pack A fragments in-register from slot cc&1 (loaded >=1 iter ago)
        bf16x8 ah[2], al[2];
        #pragma unroll
        for (int t = 0; t < 2; ++t) {
            const float4 a = xf[cc & 1][t][0];
            const float4 c = xf[cc & 1][t][1];
            u32x4 hh, ll;
            hh.x = pk_hi(a.x, a.y); hh.y = pk_hi(a.z, a.w);
            hh.z = pk_hi(c.x, c.y); hh.w = pk_hi(c.z, c.w);
            ll.x = pk_lo(a.x, a.y); ll.y = pk_lo(a.z, a.w);
            ll.z = pk_lo(c.x, c.y); ll.w = pk_lo(c.z, c.w);
            ah[t] = __builtin_bit_cast(bf16x8, hh);
            al[t] = __builtin_bit_cast(bf16x8, ll);
        }
        if (cc < 10) LOADX(cc & 1, cc + 2)   // refill slot, overlaps MFMAs

        // ---- 3-term MFMA per matrix (B-frags from resident W buffer)
#define PROJ_MAT(WTH, WTL, ACC)                                               \
        {                                                                     \
            bf16x8 bh[4], bl[4];                                              \
            _Pragma("unroll")                                                 \
            for (int nt = 0; nt < 4; ++nt) {                                  \
                const unsigned bo = (unsigned)((nt*16 + l15)*80 + quad*16);   \
                bh[nt] = *(const bf16x8*)&sm[(WTH) + bo];                     \
                bl[nt] = *(const bf16x8*)&sm[(WTL) + bo];                     \
            }                                                                 \
            _Pragma("unroll")                                                 \
            for (int mt = 0; mt < 2; ++mt)                                    \
                _Pragma("unroll")                                             \
                for (int nt = 0; nt < 4; ++nt) {                              \
                    f32x4 a = ACC[mt][nt];                                    \
                    a = MFMA16(al[mt], bh[nt], a);                            \
                    a = MFMA16(ah[mt], bl[nt], a);                            \
                    a = MFMA16(ah[mt], bh[nt], a);                            \
                    ACC[mt][nt] = a;                                          \
                }                                                             \
        }
        PROJ_MAT(bc +     0u, bc +  5120u, qac)
        PROJ_MAT(bc + 10240u, bc + 15360u, kac)
        PROJ_MAT(bc + 20480u, bc + 25600u, vac)
        __syncthreads();   // chunk cc W consumed; chunk cc+1 W staged
    }

    // ====== Phase 1 epilogue: k -> khi/klo, v -> vT, q -> A-frags ==========
    constexpr float SCALE = 19.595917942265423f;   // sqrt(384) folded into q
    // C/D layout: row = quad*4 + reg (within 16-tile), col = l15.
    #pragma unroll
    for (int mt = 0; mt < 2; ++mt) {
        const int r0m = mt ? rB : rA;
        #pragma unroll
        for (int nt = 0; nt < 4; ++nt) {
            const f32x4 kv = kac[mt][nt];
            const f32x4 vv = vac[mt][nt];
            #pragma unroll
            for (int r = 0; r < 4; ++r) {
                const int row = r0m + quad*4 + r;
                const int h   = nt*16 + l15;
                *(unsigned short*)&sm[SM_KHI + (unsigned)(row*144 + h*2)] = bhi(kv[r]);
                *(unsigned short*)&sm[SM_KLO + (unsigned)(row*144 + h*2)] = blo(kv[r]);
                *(unsigned short*)&sm[SM_VT  + (unsigned)(h*528 + row*2)] = brne(vv[r]);
            }
        }
    }

    bf16x8 qAh[2][2], qAl[2][2];
    const int slot = w & 3;
    // two shifts through 4 q-transpose slots
#define Q_XPOSE()                                                             \
    {                                                                         \
        const unsigned qb = SM_QS(slot);                                      \
        _Pragma("unroll")                                                     \
        for (int mt = 0; mt < 2; ++mt)                                        \
            _Pragma("unroll")                                                 \
            for (int nt = 0; nt < 4; ++nt) {                                  \
                const f32x4 qv = qac[mt][nt];                                 \
                _Pragma("unroll")                                             \
                for (int r = 0; r < 4; ++r) {                                 \
                    const float qs = qv[r] * SCALE;                           \
                    const int rl = mt*16 + quad*4 + r;                        \
                    const int h  = nt*16 + l15;                               \
                    *(unsigned short*)&sm[qb +         (unsigned)(rl*144 + h*2)] = bhi(qs); \
                    *(unsigned short*)&sm[qb + 4608u + (unsigned)(rl*144 + h*2)] = blo(qs); \
                }                                                             \
            }                                                                 \
        _Pragma("unroll")                                                     \
        for (int mt = 0; mt < 2; ++mt)                                        \
            _Pragma("unroll")                                                 \
            for (int ks = 0; ks < 2; ++ks) {                                  \
                const unsigned qo = (unsigned)((mt*16 + l15)*144 + ks*64 + quad*16); \
                qAh[mt][ks] = *(const bf16x8*)&sm[qb + qo];                   \
                qAl[mt][ks] = *(const bf16x8*)&sm[qb + 4608u + qo];           \
            }                                                                 \
    }
    if (w < 4) Q_XPOSE();
    __syncthreads();            // khi/klo/vT visible; slots free for waves 4..7
    if (w >= 4) Q_XPOSE();
    __syncthreads();            // q-slot area free -> becomes P slots

    // ================= Phase 2: flash attention, wave-local ================
    // Tile pairing (w, 15-w): iters = (w>>2)+1 + ((15-w)>>2)+1 == 5 for all w.
    f32x4 oac[2][4];
    float m_[2][4], l_[2][4];
    #pragma unroll
    for (int mt = 0; mt < 2; ++mt) {
        #pragma unroll
        for (int nt = 0; nt < 4; ++nt) { f32x4 z = {0.f,0.f,0.f,0.f}; oac[mt][nt] = z; }
        #pragma unroll
        for (int r = 0; r < 4; ++r) { m_[mt][r] = -1e30f; l_[mt][r] = 0.f; }
    }
    const unsigned pb = SM_PS(w);

    #pragma unroll
    for (int tile = 0; tile < 2; ++tile) {
        const int r0    = tile ? rB : rA;
        const int kbmax = tile ? ((15 - w) >> 2) : (w >> 2);
        #pragma unroll 1
        for (int kb = 0; kb <= kbmax; ++kb) {
            // ---- S = q k^T (3-term split), 16 rows x 64 keys
            bf16x8 kbh[4][2], kbl[4][2];
            #pragma unroll
            for (int nt = 0; nt < 4; ++nt)
                #pragma unroll
                for (int ks = 0; ks < 2; ++ks) {
                    const unsigned ko = (unsigned)((kb*64 + nt*16 + l15)*144 + ks*64 + quad*16);
                    kbh[nt][ks] = *(const bf16x8*)&sm[SM_KHI + ko];
                    kbl[nt][ks] = *(const bf16x8*)&sm[SM_KLO + ko];
                }
            f32x4 sac[4];
            #pragma unroll
            for (int nt = 0; nt < 4; ++nt) {
                f32x4 a = {0.f,0.f,0.f,0.f};
                #pragma unroll
                for (int ks = 0; ks < 2; ++ks) {
                    a = MFMA16(qAl[tile][ks], kbh[nt][ks], a);
                    a = MFMA16(qAh[tile][ks], kbl[nt][ks], a);
                    a = MFMA16(qAh[tile][ks], kbh[nt][ks], a);
                }
                sac[nt] = a;
            }
            // ---- causal mask on diagonal block (last kb always holds diag)
            if (kb == kbmax) {
                #pragma unroll
                for (int nt = 0; nt < 4; ++nt)
                    #pragma unroll
                    for (int r = 0; r < 4; ++r) {
                        const int rg = r0 + quad*4 + r;
                        const int kl = kb*64 + nt*16 + l15;
                        if (kl > rg) sac[nt][r] = -1e30f;
                    }
            }
            // ---- online softmax (row stats per (quad,reg); cols in lanes)
            #pragma unroll
            for (int r = 0; r < 4; ++r) {
                float v = fmaxf(fmaxf(sac[0][r], sac[1][r]), fmaxf(sac[2][r], sac[3][r]));
                v = fmaxf(v, __shfl_xor(v, 1)); v = fmaxf(v, __shfl_xor(v, 2));
                v = fmaxf(v, __shfl_xor(v, 4)); v = fmaxf(v, __shfl_xor(v, 8));
                const float mnew  = fmaxf(m_[tile][r], v);
                const float alpha = __expf(m_[tile][r] - mnew);
                m_[tile][r] = mnew;
                float rs = 0.f;
                #pragma unroll
                for (int nt = 0; nt < 4; ++nt) {
                    const float p = __expf(sac[nt][r] - mnew);
                    sac[nt][r] = p;
                    rs += p;
                }
                rs += __shfl_xor(rs, 1); rs += __shfl_xor(rs, 2);
                rs += __shfl_xor(rs, 4); rs += __shfl_xor(rs, 8);
                l_[tile][r] = l_[tile][r] * alpha + rs;
                #pragma unroll
                for (int nt = 0; nt < 4; ++nt) oac[tile][nt][r] *= alpha;
                // P -> bf16 in wave's P slot [16 rows][72 keys]
                const int rl = quad*4 + r;
                #pragma unroll
                for (int nt = 0; nt < 4; ++nt)
                    *(unsigned short*)&sm[pb + (unsigned)(rl*144 + (nt*16 + l15)*2)] =
                        brne(sac[nt][r]);
            }
            // ---- O += P V  (P via A-frags from wave slot; V from vT)
            bf16x8 pA[2], vB[4][2];
            #pragma unroll
            for (int ks = 0; ks < 2; ++ks)
                pA[ks] = *(const bf16x8*)&sm[pb + (unsigned)(l15*144 + ks*64 + quad*16)];
            #pragma unroll
            for (int nt = 0; nt < 4; ++nt)
                #pragma unroll
                for (int ks = 0; ks < 2; ++ks)
                    vB[nt][ks] = *(const bf16x8*)&sm[SM_VT + (unsigned)((nt*16 + l15)*528 + kb*128 + ks*64 + quad*16)];
            #pragma unroll
            for (int nt = 0; nt < 4; ++nt) {
                f32x4 a = oac[tile][nt];
                a = MFMA16(pA[0], vB[nt][0], a);
                a = MFMA16(pA[1], vB[nt][1], a);
                oac[tile][nt] = a;
            }
        }
    }

    // ================= Epilogue: normalize + store =========================
    float* ob = out + (size_t)b * (T_ * H_);
    #pragma unroll
    for (int mt = 0; mt < 2; ++mt) {
        const int r0m = mt ? rB : rA;
        float inv[4];
        #pragma unroll
        for (int r = 0; r < 4; ++r) inv[r] = 1.0f / l_[mt][r];
        #pragma unroll
        for (int nt = 0; nt < 4; ++nt)
            #pragma unroll
            for (int r = 0; r < 4; ++r) {
                const int row = r0m + quad*4 + r;
                const int h   = nt*16 + l15;
                ob[row*64 + h] = oac[mt][nt][r] * inv[r];
            }
    }
}

extern "C" void kernel_launch(void* const* d_in, const int* in_sizes, int n_in,
                              void* d_out, int out_size, void* d_ws, size_t ws_size,
                              hipStream_t stream)
{
    const float* x  = (const float*)d_in[0];
    const float* Wq = (const float*)d_in[1];
    const float* Wk = (const float*)d_in[2];
    const float* Wv = (const float*)d_in[3];
    // Pre-pack W (hi/lo bf16, staged-transposed) into workspace: 12*32768 = 384KB.
    wprep<<<dim3(36), dim3(256), 0, stream>>>(Wq, Wk, Wv, (unsigned char*)d_ws);
    head_mfma<<<dim3(B_), dim3(512), 0, stream>>>(x, (const unsigned char*)d_ws,
                                                  (float*)d_out);
}

// Round 7
// 326.950 us; speedup vs baseline: 1.1867x; 1.1867x over previous
//
#include <hip/hip_runtime.h>
#include <math.h>

// B=512, T=256, C=384, H=64. One block = one batch, 512 thr = 8 waves (2/SIMD).
// R10 = R9's "x never touches LDS" with the rule-#20 violation fixed: the x
// register pipeline is ONE statically-named slot (4 named float4, 16 VGPRs),
// not a runtime-indexed [cc&1] array (R9: scratch, WRITE_SIZE 33->218MB).
// Body: async W global_load_lds -> in-reg pack A-frags (chunk cc) ->
// issue x loads (chunk cc+1) -> 72 MFMAs -> barrier (drains vmcnt).
// R9's verified wins kept: bank conflicts 9.47M->7.11M, x-LDS round-trip gone.
// Numerics unchanged: 3-term bf16 hi/lo split for x,W,q,k; single bf16 P,V.
#define B_ 512
#define T_ 256
#define C_ 384
#define H_ 64

typedef __attribute__((ext_vector_type(8))) short bf16x8;
typedef __attribute__((ext_vector_type(4))) float f32x4;
typedef __attribute__((ext_vector_type(4))) unsigned u32x4;

#define MFMA16(a, b, c) __builtin_amdgcn_mfma_f32_16x16x32_bf16((a), (b), (c), 0, 0, 0)

// ---- LDS map (bytes), total 144384 <= 163840.
// Phase 1: W double-buffer WBUF(0)@0, WBUF(1)@32768 (each 32768B:
//   WQH,WQL,WKH,WKL,WVH,WVL @5120 each + 2048 pad). No x staging.
// Phase 2 (aliased over W bufs, live only after the post-loop barrier):
//   KHI@0 khi[256][72], KLO@36864, VT@73728 vT[64][264],
//   QS(s)=107520+s*9216 (4 slots, two shifts), PS(w)=107520+w*2304.
#define WBUF(i)  ((unsigned)(i)*32768u)
#define SM_KHI   0u
#define SM_KLO   36864u
#define SM_VT    73728u
#define SM_QS(s) (107520u + (unsigned)(s)*9216u)
#define SM_PS(w) (107520u + (unsigned)(w)*2304u)
#define SM_BYTES 144384u
#define WCHUNK   32768u   // ws bytes per K-chunk (30720 live + pad)

static __device__ __forceinline__ unsigned short bhi(float x) {
    return (unsigned short)(__float_as_uint(x) >> 16);            // truncate
}
static __device__ __forceinline__ unsigned short blo(float x) {
    float h = __uint_as_float((__float_as_uint(x) >> 16) << 16);
    return (unsigned short)(__float_as_uint(x - h) >> 16);        // residual
}
static __device__ __forceinline__ unsigned short brne(float x) { // round-NE
    unsigned u = __float_as_uint(x);
    return (unsigned short)((u + 0x7FFFu + ((u >> 16) & 1u)) >> 16);
}
static __device__ __forceinline__ unsigned pk_hi(float a, float b) {
    return (unsigned)bhi(a) | ((unsigned)bhi(b) << 16);
}
static __device__ __forceinline__ unsigned pk_lo(float a, float b) {
    return (unsigned)blo(a) | ((unsigned)blo(b) << 16);
}

// ---- Pre-kernel: pack W -> ws in staged-transposed layout, once for all blocks.
// ws[cc*32768 + m*10240 + part*5120 + h*80 + c'*2] = {bhi,blo}(W_m[cc*32+c'][h])
__global__ __launch_bounds__(256)
void wprep(const float* __restrict__ Wq, const float* __restrict__ Wk,
           const float* __restrict__ Wv, unsigned char* __restrict__ ws)
{
    const int cc = blockIdx.x / 3, m = blockIdx.x % 3;
    const float* W = (m == 0) ? Wq : (m == 1) ? Wk : Wv;
    const int tid = threadIdx.x;           // 256 threads
    const int c   = tid >> 3;              // 0..31 (c within chunk)
    const int h0  = (tid & 7) * 8;         // 8 h per thread
    const float* src = W + (size_t)(cc * 32 + c) * H_ + h0;
    unsigned char* dst = ws + (size_t)cc * WCHUNK + (size_t)m * 10240u;
    #pragma unroll
    for (int j = 0; j < 8; ++j) {
        const float v = src[j];
        *(unsigned short*)(dst +         (unsigned)((h0 + j) * 80 + c * 2)) = bhi(v);
        *(unsigned short*)(dst + 5120u + (unsigned)((h0 + j) * 80 + c * 2)) = blo(v);
    }
}

__global__ __launch_bounds__(512, 2)
void head_mfma(const float* __restrict__ x,
               const unsigned char* __restrict__ wpack,
               float* __restrict__ out)
{
    __shared__ __align__(16) unsigned char sm[SM_BYTES];

    const int tid  = threadIdx.x;
    const int b    = blockIdx.x;
    const int w    = tid >> 6;        // wave 0..7
    const int lane = tid & 63;
    const int l15  = lane & 15;
    const int quad = lane >> 4;
    const int rA   = w * 16;          // tile A rows [rA, rA+16)
    const int rB   = 240 - w * 16;    // tile B rows [rB, rB+16)

    // ================= Phase 1: q,k,v projections via MFMA =================
    f32x4 qac[2][4], kac[2][4], vac[2][4];
    #pragma unroll
    for (int mt = 0; mt < 2; ++mt)
        #pragma unroll
        for (int nt = 0; nt < 4; ++nt) {
            f32x4 z = {0.f, 0.f, 0.f, 0.f};
            qac[mt][nt] = z; kac[mt][nt] = z; vac[mt][nt] = z;
        }

    // per-lane A-fragment sources: row (rA|rB)+l15, 8 consecutive floats at
    // col cc*32 + quad*8. 4 quads cover a 128B-aligned row segment.
    const float* xA = x + ((size_t)b * T_ + rA + l15) * C_ + quad * 8;
    const float* xB = x + ((size_t)b * T_ + rB + l15) * C_ + quad * 8;

    // single x slot: 4 NAMED float4 (16 VGPRs, all indices compile-time)
    float4 xf_a0, xf_a1, xf_b0, xf_b1;

#define LOADX(CC)                                                             \
    {                                                                         \
        const float4* pA = (const float4*)(xA + (CC) * 32);                   \
        const float4* pB = (const float4*)(xB + (CC) * 32);                   \
        xf_a0 = pA[0]; xf_a1 = pA[1];                                         \
        xf_b0 = pB[0]; xf_b1 = pB[1];                                         \
    }
// Async W staging: per-wave uniform LDS base + lane*16, linear layout.
#define W_LDS(CC, BUF)                                                        \
    {                                                                         \
        const unsigned char* gw = wpack + (size_t)(CC) * WCHUNK;              \
        _Pragma("unroll")                                                     \
        for (int j = 0; j < 4; ++j)                                           \
            __builtin_amdgcn_global_load_lds(                                 \
                (const __attribute__((address_space(1))) void*)               \
                    (gw + (unsigned)(j*512 + tid) * 16u),                     \
                (__attribute__((address_space(3))) void*)                     \
                    &sm[(BUF) + (unsigned)(j*512 + tid) * 16u],               \
                16, 0, 0);                                                    \
    }

    // ---- prologue: W chunk0 async -> buf0; x chunk0 into regs
    W_LDS(0, WBUF(0))
    LOADX(0)
    __syncthreads();   // drains W chunk0 + x chunk0

    #pragma unroll 1
    for (int cc = 0; cc < 12; ++cc) {
        const unsigned bc = WBUF(cc & 1);   // compute W buffer (value, not index)
        if (cc < 11) W_LDS(cc + 1, WBUF((cc & 1) ^ 1))   // drains at end barrier

        // ---- pack A fragments in-register (chunk cc; loads drained at the
        //      previous barrier, so no wait here)
        bf16x8 ah[2], al[2];
        {
            u32x4 hh, ll;
            hh.x = pk_hi(xf_a0.x, xf_a0.y); hh.y = pk_hi(xf_a0.z, xf_a0.w);
            hh.z = pk_hi(xf_a1.x, xf_a1.y); hh.w = pk_hi(xf_a1.z, xf_a1.w);
            ll.x = pk_lo(xf_a0.x, xf_a0.y); ll.y = pk_lo(xf_a0.z, xf_a0.w);
            ll.z = pk_lo(xf_a1.x, xf_a1.y); ll.w = pk_lo(xf_a1.z, xf_a1.w);
            ah[0] = __builtin_bit_cast(bf16x8, hh);
            al[0] = __builtin_bit_cast(bf16x8, ll);
            hh.x = pk_hi(xf_b0.x, xf_b0.y); hh.y = pk_hi(xf_b0.z, xf_b0.w);
            hh.z = pk_hi(xf_b1.x, xf_b1.y); hh.w = pk_hi(xf_b1.z, xf_b1.w);
            ll.x = pk_lo(xf_b0.x, xf_b0.y); ll.y = pk_lo(xf_b0.z, xf_b0.w);
            ll.z = pk_lo(xf_b1.x, xf_b1.y); ll.w = pk_lo(xf_b1.z, xf_b1.w);
            ah[1] = __builtin_bit_cast(bf16x8, hh);
            al[1] = __builtin_bit_cast(bf16x8, ll);
        }
        if (cc < 11) LOADX(cc + 1)   // next chunk; completes by end barrier

        // ---- 3-term MFMA per matrix (B-frags from resident W buffer)
#define PROJ_MAT(WTH, WTL, ACC)                                               \
        {                                                                     \
            bf16x8 bh[4], bl[4];                                              \
            _Pragma("unroll")                                                 \
            for (int nt = 0; nt < 4; ++nt) {                                  \
                const unsigned bo = (unsigned)((nt*16 + l15)*80 + quad*16);   \
                bh[nt] = *(const bf16x8*)&sm[(WTH) + bo];                     \
                bl[nt] = *(const bf16x8*)&sm[(WTL) + bo];                     \
            }                                                                 \
            _Pragma("unroll")                                                 \
            for (int mt = 0; mt < 2; ++mt)                                    \
                _Pragma("unroll")                                             \
                for (int nt = 0; nt < 4; ++nt) {                              \
                    f32x4 a = ACC[mt][nt];                                    \
                    a = MFMA16(al[mt], bh[nt], a);                            \
                    a = MFMA16(ah[mt], bl[nt], a);                            \
                    a = MFMA16(ah[mt], bh[nt], a);                            \
                    ACC[mt][nt] = a;                                          \
                }                                                             \
        }
        PROJ_MAT(bc +     0u, bc +  5120u, qac)
        PROJ_MAT(bc + 10240u, bc + 15360u, kac)
        PROJ_MAT(bc + 20480u, bc + 25600u, vac)
        __syncthreads();   // chunk cc W consumed; chunk cc+1 (W + x) staged
    }

    // ====== Phase 1 epilogue: k -> khi/klo, v -> vT, q -> A-frags ==========
    constexpr float SCALE = 19.595917942265423f;   // sqrt(384) folded into q
    // C/D layout: row = quad*4 + reg (within 16-tile), col = l15.
    #pragma unroll
    for (int mt = 0; mt < 2; ++mt) {
        const int r0m = mt ? rB : rA;
        #pragma unroll
        for (int nt = 0; nt < 4; ++nt) {
            const f32x4 kv = kac[mt][nt];
            const f32x4 vv = vac[mt][nt];
            #pragma unroll
            for (int r = 0; r < 4; ++r) {
                const int row = r0m + quad*4 + r;
                const int h   = nt*16 + l15;
                *(unsigned short*)&sm[SM_KHI + (unsigned)(row*144 + h*2)] = bhi(kv[r]);
                *(unsigned short*)&sm[SM_KLO + (unsigned)(row*144 + h*2)] = blo(kv[r]);
                *(unsigned short*)&sm[SM_VT  + (unsigned)(h*528 + row*2)] = brne(vv[r]);
            }
        }
    }

    bf16x8 qAh[2][2], qAl[2][2];
    const int slot = w & 3;
    // two shifts through 4 q-transpose slots
#define Q_XPOSE()                                                             \
    {                                                                         \
        const unsigned qb = SM_QS(slot);                                      \
        _Pragma("unroll")                                                     \
        for (int mt = 0; mt < 2; ++mt)                                        \
            _Pragma("unroll")                                                 \
            for (int nt = 0; nt < 4; ++nt) {                                  \
                const f32x4 qv = qac[mt][nt];                                 \
                _Pragma("unroll")                                             \
                for (int r = 0; r < 4; ++r) {                                 \
                    const float qs = qv[r] * SCALE;                           \
                    const int rl = mt*16 + quad*4 + r;                        \
                    const int h  = nt*16 + l15;                               \
                    *(unsigned short*)&sm[qb +         (unsigned)(rl*144 + h*2)] = bhi(qs); \
                    *(unsigned short*)&sm[qb + 4608u + (unsigned)(rl*144 + h*2)] = blo(qs); \
                }                                                             \
            }                                                                 \
        _Pragma("unroll")                                                     \
        for (int mt = 0; mt < 2; ++mt)                                        \
            _Pragma("unroll")                                                 \
            for (int ks = 0; ks < 2; ++ks) {                                  \
                const unsigned qo = (unsigned)((mt*16 + l15)*144 + ks*64 + quad*16); \
                qAh[mt][ks] = *(const bf16x8*)&sm[qb + qo];                   \
                qAl[mt][ks] = *(const bf16x8*)&sm[qb + 4608u + qo];           \
            }                                                                 \
    }
    if (w < 4) Q_XPOSE();
    __syncthreads();            // khi/klo/vT visible; slots free for waves 4..7
    if (w >= 4) Q_XPOSE();
    __syncthreads();            // q-slot area free -> becomes P slots

    // ================= Phase 2: flash attention, wave-local ================
    // Tile pairing (w, 15-w): iters = (w>>2)+1 + ((15-w)>>2)+1 == 5 for all w.
    f32x4 oac[2][4];
    float m_[2][4], l_[2][4];
    #pragma unroll
    for (int mt = 0; mt < 2; ++mt) {
        #pragma unroll
        for (int nt = 0; nt < 4; ++nt) { f32x4 z = {0.f,0.f,0.f,0.f}; oac[mt][nt] = z; }
        #pragma unroll
        for (int r = 0; r < 4; ++r) { m_[mt][r] = -1e30f; l_[mt][r] = 0.f; }
    }
    const unsigned pb = SM_PS(w);

    #pragma unroll
    for (int tile = 0; tile < 2; ++tile) {
        const int r0    = tile ? rB : rA;
        const int kbmax = tile ? ((15 - w) >> 2) : (w >> 2);
        #pragma unroll 1
        for (int kb = 0; kb <= kbmax; ++kb) {
            // ---- S = q k^T (3-term split), 16 rows x 64 keys
            bf16x8 kbh[4][2], kbl[4][2];
            #pragma unroll
            for (int nt = 0; nt < 4; ++nt)
                #pragma unroll
                for (int ks = 0; ks < 2; ++ks) {
                    const unsigned ko = (unsigned)((kb*64 + nt*16 + l15)*144 + ks*64 + quad*16);
                    kbh[nt][ks] = *(const bf16x8*)&sm[SM_KHI + ko];
                    kbl[nt][ks] = *(const bf16x8*)&sm[SM_KLO + ko];
                }
            f32x4 sac[4];
            #pragma unroll
            for (int nt = 0; nt < 4; ++nt) {
                f32x4 a = {0.f,0.f,0.f,0.f};
                #pragma unroll
                for (int ks = 0; ks < 2; ++ks) {
                    a = MFMA16(qAl[tile][ks], kbh[nt][ks], a);
                    a = MFMA16(qAh[tile][ks], kbl[nt][ks], a);
                    a = MFMA16(qAh[tile][ks], kbh[nt][ks], a);
                }
                sac[nt] = a;
            }
            // ---- causal mask on diagonal block (last kb always holds diag)
            if (kb == kbmax) {
                #pragma unroll
                for (int nt = 0; nt < 4; ++nt)
                    #pragma unroll
                    for (int r = 0; r < 4; ++r) {
                        const int rg = r0 + quad*4 + r;
                        const int kl = kb*64 + nt*16 + l15;
                        if (kl > rg) sac[nt][r] = -1e30f;
                    }
            }
            // ---- online softmax (row stats per (quad,reg); cols in lanes)
            #pragma unroll
            for (int r = 0; r < 4; ++r) {
                float v = fmaxf(fmaxf(sac[0][r], sac[1][r]), fmaxf(sac[2][r], sac[3][r]));
                v = fmaxf(v, __shfl_xor(v, 1)); v = fmaxf(v, __shfl_xor(v, 2));
                v = fmaxf(v, __shfl_xor(v, 4)); v = fmaxf(v, __shfl_xor(v, 8));
                const float mnew  = fmaxf(m_[tile][r], v);
                const float alpha = __expf(m_[tile][r] - mnew);
                m_[tile][r] = mnew;
                float rs = 0.f;
                #pragma unroll
                for (int nt = 0; nt < 4; ++nt) {
                    const float p = __expf(sac[nt][r] - mnew);
                    sac[nt][r] = p;
                    rs += p;
                }
                rs += __shfl_xor(rs, 1); rs += __shfl_xor(rs, 2);
                rs += __shfl_xor(rs, 4); rs += __shfl_xor(rs, 8);
                l_[tile][r] = l_[tile][r] * alpha + rs;
                #pragma unroll
                for (int nt = 0; nt < 4; ++nt) oac[tile][nt][r] *= alpha;
                // P -> bf16 in wave's P slot [16 rows][72 keys]
                const int rl = quad*4 + r;
                #pragma unroll
                for (int nt = 0; nt < 4; ++nt)
                    *(unsigned short*)&sm[pb + (unsigned)(rl*144 + (nt*16 + l15)*2)] =
                        brne(sac[nt][r]);
            }
            // ---- O += P V  (P via A-frags from wave slot; V from vT)
            bf16x8 pA[2], vB[4][2];
            #pragma unroll
            for (int ks = 0; ks < 2; ++ks)
                pA[ks] = *(const bf16x8*)&sm[pb + (unsigned)(l15*144 + ks*64 + quad*16)];
            #pragma unroll
            for (int nt = 0; nt < 4; ++nt)
                #pragma unroll
                for (int ks = 0; ks < 2; ++ks)
                    vB[nt][ks] = *(const bf16x8*)&sm[SM_VT + (unsigned)((nt*16 + l15)*528 + kb*128 + ks*64 + quad*16)];
            #pragma unroll
            for (int nt = 0; nt < 4; ++nt) {
                f32x4 a = oac[tile][nt];
                a = MFMA16(pA[0], vB[nt][0], a);
                a = MFMA16(pA[1], vB[nt][1], a);
                oac[tile][nt] = a;
            }
        }
    }

    // ================= Epilogue: normalize + store =========================
    float* ob = out + (size_t)b * (T_ * H_);
    #pragma unroll
    for (int mt = 0; mt < 2; ++mt) {
        const int r0m = mt ? rB : rA;
        float inv[4];
        #pragma unroll
        for (int r = 0; r < 4; ++r) inv[r] = 1.0f / l_[mt][r];
        #pragma unroll
        for (int nt = 0; nt < 4; ++nt)
            #pragma unroll
            for (int r = 0; r < 4; ++r) {
                const int row = r0m + quad*4 + r;
                const int h   = nt*16 + l15;
                ob[row*64 + h] = oac[mt][nt][r] * inv[r];
            }
    }
}

extern "C" void kernel_launch(void* const* d_in, const int* in_sizes, int n_in,
                              void* d_out, int out_size, void* d_ws, size_t ws_size,
                              hipStream_t stream)
{
    const float* x  = (const float*)d_in[0];
    const float* Wq = (const float*)d_in[1];
    const float* Wk = (const float*)d_in[2];
    const float* Wv = (const float*)d_in[3];
    // Pre-pack W (hi/lo bf16, staged-transposed) into workspace: 12*32768 = 384KB.
    wprep<<<dim3(36), dim3(256), 0, stream>>>(Wq, Wk, Wv, (unsigned char*)d_ws);
    head_mfma<<<dim3(B_), dim3(512), 0, stream>>>(x, (const unsigned char*)d_ws,
                                                  (float*)d_out);
}